// Round 2
// baseline (238.638 us; speedup 1.0000x reference)
//
#include <hip/hip_runtime.h>
#include <hip/hip_fp16.h>

#define N_NODES 50000
#define N_EDGES 1600000
#define IN_DIM 256
#define OUT_DIM 128
#define NEG_SLOPE 0.01f

// ---- two-level radix geometry ----
#define BIN_SH    7
#define BIN_ROWS  128                                   // rows per bin
#define NBIN      ((N_NODES + BIN_ROWS - 1) / BIN_ROWS) // 391
#define CAPB      4864                                  // mean 4096, sd 64 -> +12 sigma
#define ROWOFF_N  (NBIN * BIN_ROWS + 1)                 // 50049

#define GBLK_ROWS 32
#define NGBLK     ((N_NODES + GBLK_ROWS - 1) / GBLK_ROWS) // 1563 gather blocks

#define HIST_BLOCKS 512
#define CONVW_BLOCKS 16                  // extra blocks: W fp32 -> f16 frag layout
#define EPB_H (N_EDGES / HIST_BLOCKS)    // 3125
#define SCAT_BLOCKS 512
#define EPB_S (N_EDGES / SCAT_BLOCKS)    // 3125
#define SCAT_ITERS ((EPB_S + 511) / 512) // 7

typedef _Float16 f16x8 __attribute__((ext_vector_type(8)));
typedef float    f32x4 __attribute__((ext_vector_type(4)));
typedef float    f32x8 __attribute__((ext_vector_type(8)));

__device__ __forceinline__ float lrelu(float v) {
    return v >= 0.f ? v : NEG_SLOPE * v;
}

// ---------------------------------------------------------------------------
// Kernel 1: h = x @ W via v_mfma_f32_16x16x32_f16 (f16 inputs, fp32 accum).
// Unchanged from round 1 (dropped out of top-5; ~13 us, memory-bound).
// ---------------------------------------------------------------------------
#define BM 128
#define GEMM_BLOCKS ((N_NODES + BM - 1) / BM)   // 391

#define CVT16(lo, hi) do { \
    lo[0]=(_Float16)xr[0].x; lo[1]=(_Float16)xr[0].y; lo[2]=(_Float16)xr[0].z; lo[3]=(_Float16)xr[0].w; \
    lo[4]=(_Float16)xr[1].x; lo[5]=(_Float16)xr[1].y; lo[6]=(_Float16)xr[1].z; lo[7]=(_Float16)xr[1].w; \
    hi[0]=(_Float16)xr[2].x; hi[1]=(_Float16)xr[2].y; hi[2]=(_Float16)xr[2].z; hi[3]=(_Float16)xr[2].w; \
    hi[4]=(_Float16)xr[3].x; hi[5]=(_Float16)xr[3].y; hi[6]=(_Float16)xr[3].z; hi[7]=(_Float16)xr[3].w; \
} while (0)

__global__ __launch_bounds__(256, 2) void gemm_xw_mfma(const float* __restrict__ x,
                                                       const __half* __restrict__ wtl,
                                                       __half* __restrict__ h) {
    __shared__ f16x8 wt8[32 * 128];   // [kgi=k/8][n] -> 8 halves k..k+7 : 64 KB
    __shared__ f16x8 xs8[2][4][BM];   // [buf][kg][m] -> 8 halves         : 16 KB

    const int t    = threadIdx.x;
    const int lane = t & 63;
    const int wv   = t >> 6;
    const int row0 = blockIdx.x * BM;

    {
        const int4* src = (const int4*)wtl;
        int4* dst = (int4*)wt8;
#pragma unroll
        for (int i = 0; i < 16; ++i) dst[i * 256 + t] = src[i * 256 + t];
    }

    const int srow = t >> 1;
    const int skh  = t & 1;
    const int grow = row0 + srow;
    const bool rv  = grow < N_NODES;
    const float* xp = x + (size_t)(rv ? grow : 0) * IN_DIM + skh * 16;

    float4 xr[4];
#pragma unroll
    for (int i = 0; i < 4; ++i)
        xr[i] = rv ? ((const float4*)xp)[i] : make_float4(0.f, 0.f, 0.f, 0.f);
    {
        f16x8 lo, hi;
        CVT16(lo, hi);
        xs8[0][skh * 2 + 0][srow] = lo;
        xs8[0][skh * 2 + 1][srow] = hi;
    }
    __syncthreads();

    f32x4 acc[2][8];
#pragma unroll
    for (int mf = 0; mf < 2; ++mf)
#pragma unroll
        for (int nf = 0; nf < 8; ++nf) acc[mf][nf] = (f32x4){0.f, 0.f, 0.f, 0.f};

    const int kg  = lane >> 4;
    const int l15 = lane & 15;
    const int mb  = (wv << 5) + l15;

#pragma unroll
    for (int ks = 0; ks < 8; ++ks) {
        const int cur = ks & 1;
        if (ks < 7) {
#pragma unroll
            for (int i = 0; i < 4; ++i)
                xr[i] = rv ? ((const float4*)(xp + (ks + 1) * 32))[i]
                           : make_float4(0.f, 0.f, 0.f, 0.f);
        }
        const f16x8 b0 = xs8[cur][kg][mb];
        const f16x8 b1 = xs8[cur][kg][mb + 16];
#pragma unroll
        for (int nf = 0; nf < 8; ++nf) {
            const f16x8 a = wt8[(((ks << 2) | kg) << 7) + (nf << 4) + l15];
            acc[0][nf] = __builtin_amdgcn_mfma_f32_16x16x32_f16(a, b0, acc[0][nf], 0, 0, 0);
            acc[1][nf] = __builtin_amdgcn_mfma_f32_16x16x32_f16(a, b1, acc[1][nf], 0, 0, 0);
        }
        if (ks < 7) {
            f16x8 lo, hi;
            CVT16(lo, hi);
            xs8[cur ^ 1][skh * 2 + 0][srow] = lo;
            xs8[cur ^ 1][skh * 2 + 1][srow] = hi;
            __syncthreads();
        }
    }

    const int rg = lane >> 4;
#pragma unroll
    for (int mf = 0; mf < 2; ++mf) {
        const int m = row0 + (wv << 5) + (mf << 4) + l15;
        if (m < N_NODES) {
            __half* hp = h + (size_t)m * OUT_DIM + (rg << 2);
#pragma unroll
            for (int nf = 0; nf < 8; ++nf) {
                union { ushort4 u; __half f[4]; } o;
                o.f[0] = __float2half(acc[mf][nf][0]);
                o.f[1] = __float2half(acc[mf][nf][1]);
                o.f[2] = __float2half(acc[mf][nf][2]);
                o.f[3] = __float2half(acc[mf][nf][3]);
                *(ushort4*)(hp + (nf << 4)) = o.u;
            }
        }
    }
}

// ---------------------------------------------------------------------------
// Kernel 2: per-BIN histogram (blocks 0..511) + W fp32->f16 frag transform
// (blocks 512..527, hides under the histogram; must precede gemm).
// ---------------------------------------------------------------------------
__global__ __launch_bounds__(256) void bucket_hist(const int* __restrict__ rows,
                                                   int* __restrict__ counts,
                                                   const float* __restrict__ w,
                                                   __half* __restrict__ wtl) {
    if (blockIdx.x >= HIST_BLOCKS) {
        const int e0 = ((blockIdx.x - HIST_BLOCKS) * 256 + threadIdx.x) * 8;
        const int k  = e0 >> 7;
        const int n0 = e0 & 127;
        const float4 a = *(const float4*)(w + e0);
        const float4 b = *(const float4*)(w + e0 + 4);
        __half* dst = wtl + ((size_t)((k >> 3) * 128 + n0)) * 8 + (k & 7);
        dst[0]  = __float2half(a.x);
        dst[8]  = __float2half(a.y);
        dst[16] = __float2half(a.z);
        dst[24] = __float2half(a.w);
        dst[32] = __float2half(b.x);
        dst[40] = __float2half(b.y);
        dst[48] = __float2half(b.z);
        dst[56] = __float2half(b.w);
        return;
    }

    __shared__ int lhist[NBIN];
    const int t = threadIdx.x;
    const int ebase = blockIdx.x * EPB_H;

    for (int b = t; b < NBIN; b += 256) lhist[b] = 0;
    __syncthreads();

    for (int k = 0; k < EPB_H; k += 256) {
        if (k + t < EPB_H) atomicAdd(&lhist[rows[ebase + k + t] >> BIN_SH], 1);
    }
    __syncthreads();

    for (int b = t; b < NBIN; b += 256) {
        const int c = lhist[b];
        if (c > 0) atomicAdd(&counts[b], c);
    }
}

// ---------------------------------------------------------------------------
// Kernel 3: coarse scatter into 391 bins of 128 rows. Each block locally
// scans counts[] (1.6 KB, L2-broadcast) -> bin offsets, so no separate scan
// kernel. Runs per block*bin ~8 records (64 B) -> write amp ~2x (vs 4.2x),
// global atomics 200K (vs 800K). 512 thr * 512 blk = 16 waves/CU.
// Record: { col | (row & 127) << 16 , val_bits }.
// ---------------------------------------------------------------------------
__global__ __launch_bounds__(512) void scatter_bins(const int* __restrict__ rows,
                                                    const int* __restrict__ cols,
                                                    const float* __restrict__ vals,
                                                    const int* __restrict__ counts,
                                                    int* __restrict__ cursor,
                                                    int2* __restrict__ ebuf) {
    __shared__ int sb[512];
    __shared__ int lbase[NBIN];
    const int t = threadIdx.x;
    const int ebase = blockIdx.x * EPB_S;

    // local exclusive scan of bin counts -> bin base offsets
    sb[t] = (t < NBIN) ? counts[t] : 0;
    const int myc = sb[t];
    __syncthreads();
    for (int off = 1; off < 512; off <<= 1) {
        const int u = (t >= off) ? sb[t - off] : 0;
        __syncthreads();
        sb[t] += u;
        __syncthreads();
    }
    if (t < NBIN) lbase[t] = sb[t] - myc;
    __syncthreads();
    if (t < NBIN) sb[t] = 0;           // reuse sb as local per-bin count
    __syncthreads();

    int myr[SCAT_ITERS];
#pragma unroll
    for (int k = 0; k < SCAT_ITERS; ++k) {
        const int i = k * 512 + t;
        myr[k] = -1;
        if (i < EPB_S) {
            const int r = rows[ebase + i];
            myr[k] = r;
            atomicAdd(&sb[r >> BIN_SH], 1);
        }
    }
    __syncthreads();

    if (t < NBIN) {
        const int c = sb[t];
        sb[t] = (c > 0) ? (lbase[t] + atomicAdd(&cursor[t], c)) : 0;
    }
    __syncthreads();

#pragma unroll
    for (int k = 0; k < SCAT_ITERS; ++k) {
        const int i = k * 512 + t;
        if (i < EPB_S) {
            const int e = ebase + i;
            const int r = myr[k];
            const int pos = atomicAdd(&sb[r >> BIN_SH], 1);
            ebuf[pos] = make_int2(cols[e] | ((r & (BIN_ROWS - 1)) << 16), __float_as_int(vals[e]));
        }
    }
}

// ---------------------------------------------------------------------------
// Kernel 4: per-bin in-place counting sort by row + rowoff (row CSR) emit.
// One block per bin: stage bin records in LDS (no in-place hazard: phase 2
// reads LDS, writes global), 128-row hist + scan, write rowoff, permute.
// Overflow (> +12 sigma, statistically unreachable): flag bin, leave records
// unsorted (format identical), still emit correct rowoff counts.
// ---------------------------------------------------------------------------
__global__ __launch_bounds__(512) void sort_bins(const int* __restrict__ counts,
                                                 int2* __restrict__ ebuf,
                                                 int* __restrict__ rowoff,
                                                 int* __restrict__ ovf) {
    __shared__ int2 srec[CAPB];            // 38 KB
    __shared__ int sb[512];
    __shared__ int hist[BIN_ROWS];
    __shared__ int pfx[BIN_ROWS];
    __shared__ int s_base, s_cnt;

    const int t   = threadIdx.x;
    const int bin = blockIdx.x;

    sb[t] = (t < NBIN) ? counts[t] : 0;
    const int myc = sb[t];
    __syncthreads();
    for (int off = 1; off < 512; off <<= 1) {
        const int u = (t >= off) ? sb[t - off] : 0;
        __syncthreads();
        sb[t] += u;
        __syncthreads();
    }
    if (t == bin) { s_base = sb[t] - myc; s_cnt = myc; }
    if (t < BIN_ROWS) hist[t] = 0;
    __syncthreads();
    const int base = s_base;
    const int cnt  = s_cnt;

    if (cnt <= CAPB) {
        for (int i = t; i < cnt; i += 512) {
            const int2 r = ebuf[base + i];
            srec[i] = r;
            atomicAdd(&hist[(r.x >> 16) & (BIN_ROWS - 1)], 1);
        }
        __syncthreads();

        if (t < BIN_ROWS) pfx[t] = hist[t];
        __syncthreads();
        for (int off = 1; off < BIN_ROWS; off <<= 1) {
            const int u = (t >= off && t < BIN_ROWS) ? pfx[t - off] : 0;
            __syncthreads();
            if (t < BIN_ROWS) pfx[t] += u;
            __syncthreads();
        }
        if (t < BIN_ROWS) {
            const int excl = pfx[t] - hist[t];
            rowoff[(bin << BIN_SH) + t] = base + excl;
            if (t == BIN_ROWS - 1) rowoff[(bin << BIN_SH) + BIN_ROWS] = base + cnt;
            hist[t] = excl;                 // sort cursor
        }
        __syncthreads();

        for (int i = t; i < cnt; i += 512) {
            const int2 r = srec[i];
            const int pos = base + atomicAdd(&hist[(r.x >> 16) & (BIN_ROWS - 1)], 1);
            ebuf[pos] = r;
        }
    } else {
        if (t == 0) ovf[bin] = 1;
        for (int i = t; i < cnt; i += 512)
            atomicAdd(&hist[(ebuf[base + i].x >> 16) & (BIN_ROWS - 1)], 1);
        __syncthreads();
        if (t < BIN_ROWS) pfx[t] = hist[t];
        __syncthreads();
        for (int off = 1; off < BIN_ROWS; off <<= 1) {
            const int u = (t >= off && t < BIN_ROWS) ? pfx[t - off] : 0;
            __syncthreads();
            if (t < BIN_ROWS) pfx[t] += u;
            __syncthreads();
        }
        if (t < BIN_ROWS) {
            rowoff[(bin << BIN_SH) + t] = base + (pfx[t] - hist[t]);
            if (t == BIN_ROWS - 1) rowoff[(bin << BIN_SH) + BIN_ROWS] = base + cnt;
        }
    }
}

// ---------------------------------------------------------------------------
// Kernel 5: sort-free gather. Block = 32 rows; wave = 8 rows, processed in
// pairs for MLP. 16 lanes per edge read f16x8 (16 B/lane), 4 edges per wave
// memory instruction -> 4x fewer VMEM issues than round-1 gather. Row-end
// cross-group shfl_xor reduce; fused leaky-ReLU; no LDS, no atomics.
// ---------------------------------------------------------------------------
__global__ __launch_bounds__(256) void gather_rows(const __half* __restrict__ h,
                                                   const int* __restrict__ rowoff,
                                                   const int2* __restrict__ ebuf,
                                                   const int* __restrict__ ovf,
                                                   float* __restrict__ out) {
    const int t    = threadIdx.x;
    const int w    = t >> 6;
    const int lane = t & 63;
    const int grp  = lane >> 4;        // 0..3: edge slot within 4-edge group
    const int gl   = lane & 15;        // 16 lanes span one 256 B h row
    const int bkt  = blockIdx.x;
    const int bin  = bkt >> 2;         // 4 gather blocks per 128-row bin
    const int rbase = bkt * GBLK_ROWS + w * 8;

    if (ovf[bin]) {
        // correctness net: bin unsorted -> filter-scan whole bin (64 lanes/row)
        const int bb = rowoff[bin << BIN_SH];
        const int be = rowoff[(bin << BIN_SH) + BIN_ROWS];
        for (int rr = 0; rr < 8; ++rr) {
            const int row = rbase + rr;
            float2 acc = make_float2(0.f, 0.f);
            for (int e = bb; e < be; ++e) {
                const int2 rec = ebuf[e];
                if (((rec.x >> 16) & (BIN_ROWS - 1)) == (row & (BIN_ROWS - 1))) {
                    const float2 m = __half22float2(((const __half2*)(h + (size_t)(rec.x & 0xFFFF) * OUT_DIM))[lane]);
                    const float v = __int_as_float(rec.y);
                    acc.x += v * m.x; acc.y += v * m.y;
                }
            }
            if (row < N_NODES) {
                acc.x = lrelu(acc.x); acc.y = lrelu(acc.y);
                ((float2*)(out + (size_t)row * OUT_DIM))[lane] = acc;
            }
        }
        return;
    }

    for (int p = 0; p < 4; ++p) {
        const int r0 = rbase + 2 * p;
        const int r1 = r0 + 1;
        const int b0 = rowoff[r0], e0 = rowoff[r0 + 1];
        const int b1 = rowoff[r1], e1 = rowoff[r1 + 1];
        const int n0 = e0 - b0, n1 = e1 - b1;
        const int nmax = n0 > n1 ? n0 : n1;
        const int iters = (nmax + 3) >> 2;

        f32x8 a0 = (f32x8){0.f,0.f,0.f,0.f,0.f,0.f,0.f,0.f};
        f32x8 a1 = (f32x8){0.f,0.f,0.f,0.f,0.f,0.f,0.f,0.f};

        for (int it = 0; it < iters; ++it) {
            const int i0 = b0 + (it << 2) + grp;
            const int i1 = b1 + (it << 2) + grp;
            const bool v0i = i0 < e0;
            const bool v1i = i1 < e1;
            const int2 rA = ebuf[v0i ? i0 : 0];
            const int2 rB = ebuf[v1i ? i1 : 0];
            const float vA = v0i ? __int_as_float(rA.y) : 0.f;
            const float vB = v1i ? __int_as_float(rB.y) : 0.f;
            const f16x8 hA = *(const f16x8*)(h + (size_t)(rA.x & 0xFFFF) * OUT_DIM + (gl << 3));
            const f16x8 hB = *(const f16x8*)(h + (size_t)(rB.x & 0xFFFF) * OUT_DIM + (gl << 3));
#pragma unroll
            for (int j = 0; j < 8; ++j) {
                a0[j] += vA * (float)hA[j];
                a1[j] += vB * (float)hB[j];
            }
        }

        // reduce partial sums across the 4 groups (lanes l, l+16, l+32, l+48)
#pragma unroll
        for (int j = 0; j < 8; ++j) {
            float x0 = a0[j], x1 = a1[j];
            x0 += __shfl_xor(x0, 16); x0 += __shfl_xor(x0, 32);
            x1 += __shfl_xor(x1, 16); x1 += __shfl_xor(x1, 32);
            a0[j] = x0; a1[j] = x1;
        }

        // grp 0/1 store row0 lo/hi float4, grp 2/3 store row1 lo/hi float4
        const int row = (grp & 2) ? r1 : r0;
        float q[4];
#pragma unroll
        for (int k = 0; k < 4; ++k) {
            const float lo = (grp & 2) ? a1[k]     : a0[k];
            const float hi = (grp & 2) ? a1[k + 4] : a0[k + 4];
            q[k] = lrelu((grp & 1) ? hi : lo);
        }
        if (row < N_NODES) {
            float4 o = make_float4(q[0], q[1], q[2], q[3]);
            *(float4*)(out + (size_t)row * OUT_DIM + (gl << 3) + ((grp & 1) << 2)) = o;
        }
    }
}

// ---------------------------------------------------------------------------
// Launch. hist(+W-convert) -> gemm -> scatter_bins -> sort_bins -> gather.
// One memset covers counts + cursor + ovf (contiguous meta region).
// ---------------------------------------------------------------------------
extern "C" void kernel_launch(void* const* d_in, const int* in_sizes, int n_in,
                              void* d_out, int out_size, void* d_ws, size_t ws_size,
                              hipStream_t stream) {
    const float* x    = (const float*)d_in[0];
    const float* w    = (const float*)d_in[1];
    const float* vals = (const float*)d_in[2];
    const int*   rows = (const int*)d_in[3];
    const int*   cols = (const int*)d_in[4];
    float* out = (float*)d_out;

    char* ws = (char*)d_ws;
    size_t off = 0;
    auto alloc = [&](size_t bytes) {
        void* p = ws + off;
        off = (off + bytes + 255) & ~(size_t)255;
        return p;
    };
    __half* h      = (__half*)alloc((size_t)N_NODES * OUT_DIM * sizeof(__half)); // 12.8 MB
    int2*  ebuf    = (int2*) alloc((size_t)N_EDGES * sizeof(int2));              // 12.8 MB
    __half* wtl    = (__half*)alloc((size_t)IN_DIM * OUT_DIM * sizeof(__half));  // 64 KB
    int*   rowoff  = (int*)  alloc((size_t)ROWOFF_N * sizeof(int));              // 200 KB
    int*   meta    = (int*)  alloc((size_t)(3 * NBIN) * sizeof(int));            // counts|cursor|ovf
    int*   counts  = meta;
    int*   cursor  = meta + NBIN;
    int*   ovfl    = meta + 2 * NBIN;

    hipMemsetAsync(meta, 0, (size_t)(3 * NBIN) * sizeof(int), stream);

    bucket_hist<<<HIST_BLOCKS + CONVW_BLOCKS, 256, 0, stream>>>(rows, counts, w, wtl);
    gemm_xw_mfma<<<GEMM_BLOCKS, 256, 0, stream>>>(x, wtl, h);
    scatter_bins<<<SCAT_BLOCKS, 512, 0, stream>>>(rows, cols, vals, counts, cursor, ebuf);
    sort_bins<<<NBIN, 512, 0, stream>>>(counts, ebuf, rowoff, ovfl);
    gather_rows<<<NGBLK, 256, 0, stream>>>(h, rowoff, ebuf, ovfl, out);
}

// Round 3
// 228.349 us; speedup vs baseline: 1.0451x; 1.0451x over previous
//
#include <hip/hip_runtime.h>
#include <hip/hip_fp16.h>

#define N_NODES 50000
#define N_EDGES 1600000
#define IN_DIM 256
#define OUT_DIM 128
#define NEG_SLOPE 0.01f

// ---- two-level radix geometry ----
#define BIN_SH    7
#define BIN_ROWS  128                                   // rows per bin
#define NBIN      ((N_NODES + BIN_ROWS - 1) / BIN_ROWS) // 391
#define CAPB      4864                                  // mean 4096, sd 64 -> +12 sigma

#define HIST_BLOCKS 512
#define CONVW_BLOCKS 16                  // extra blocks: W fp32 -> f16 frag layout
#define EPB_H (N_EDGES / HIST_BLOCKS)    // 3125
#define SCAT_BLOCKS 512
#define EPB_S (N_EDGES / SCAT_BLOCKS)    // 3125
#define SCAT_ITERS ((EPB_S + 511) / 512) // 7

typedef _Float16 f16x8 __attribute__((ext_vector_type(8)));
typedef float    f32x4 __attribute__((ext_vector_type(4)));
typedef float    f32x8 __attribute__((ext_vector_type(8)));

__device__ __forceinline__ float lrelu(float v) {
    return v >= 0.f ? v : NEG_SLOPE * v;
}

// ---------------------------------------------------------------------------
// Kernel 1: h = x @ W via v_mfma_f32_16x16x32_f16 (f16 inputs, fp32 accum).
// ~29 us (est. from round-0->1 delta), memory-bound on 51 MB x-read.
// ---------------------------------------------------------------------------
#define BM 128
#define GEMM_BLOCKS ((N_NODES + BM - 1) / BM)   // 391

#define CVT16(lo, hi) do { \
    lo[0]=(_Float16)xr[0].x; lo[1]=(_Float16)xr[0].y; lo[2]=(_Float16)xr[0].z; lo[3]=(_Float16)xr[0].w; \
    lo[4]=(_Float16)xr[1].x; lo[5]=(_Float16)xr[1].y; lo[6]=(_Float16)xr[1].z; lo[7]=(_Float16)xr[1].w; \
    hi[0]=(_Float16)xr[2].x; hi[1]=(_Float16)xr[2].y; hi[2]=(_Float16)xr[2].z; hi[3]=(_Float16)xr[2].w; \
    hi[4]=(_Float16)xr[3].x; hi[5]=(_Float16)xr[3].y; hi[6]=(_Float16)xr[3].z; hi[7]=(_Float16)xr[3].w; \
} while (0)

__global__ __launch_bounds__(256, 2) void gemm_xw_mfma(const float* __restrict__ x,
                                                       const __half* __restrict__ wtl,
                                                       __half* __restrict__ h) {
    __shared__ f16x8 wt8[32 * 128];   // [kgi=k/8][n] -> 8 halves k..k+7 : 64 KB
    __shared__ f16x8 xs8[2][4][BM];   // [buf][kg][m] -> 8 halves         : 16 KB

    const int t    = threadIdx.x;
    const int lane = t & 63;
    const int wv   = t >> 6;
    const int row0 = blockIdx.x * BM;

    {
        const int4* src = (const int4*)wtl;
        int4* dst = (int4*)wt8;
#pragma unroll
        for (int i = 0; i < 16; ++i) dst[i * 256 + t] = src[i * 256 + t];
    }

    const int srow = t >> 1;
    const int skh  = t & 1;
    const int grow = row0 + srow;
    const bool rv  = grow < N_NODES;
    const float* xp = x + (size_t)(rv ? grow : 0) * IN_DIM + skh * 16;

    float4 xr[4];
#pragma unroll
    for (int i = 0; i < 4; ++i)
        xr[i] = rv ? ((const float4*)xp)[i] : make_float4(0.f, 0.f, 0.f, 0.f);
    {
        f16x8 lo, hi;
        CVT16(lo, hi);
        xs8[0][skh * 2 + 0][srow] = lo;
        xs8[0][skh * 2 + 1][srow] = hi;
    }
    __syncthreads();

    f32x4 acc[2][8];
#pragma unroll
    for (int mf = 0; mf < 2; ++mf)
#pragma unroll
        for (int nf = 0; nf < 8; ++nf) acc[mf][nf] = (f32x4){0.f, 0.f, 0.f, 0.f};

    const int kg  = lane >> 4;
    const int l15 = lane & 15;
    const int mb  = (wv << 5) + l15;

#pragma unroll
    for (int ks = 0; ks < 8; ++ks) {
        const int cur = ks & 1;
        if (ks < 7) {
#pragma unroll
            for (int i = 0; i < 4; ++i)
                xr[i] = rv ? ((const float4*)(xp + (ks + 1) * 32))[i]
                           : make_float4(0.f, 0.f, 0.f, 0.f);
        }
        const f16x8 b0 = xs8[cur][kg][mb];
        const f16x8 b1 = xs8[cur][kg][mb + 16];
#pragma unroll
        for (int nf = 0; nf < 8; ++nf) {
            const f16x8 a = wt8[(((ks << 2) | kg) << 7) + (nf << 4) + l15];
            acc[0][nf] = __builtin_amdgcn_mfma_f32_16x16x32_f16(a, b0, acc[0][nf], 0, 0, 0);
            acc[1][nf] = __builtin_amdgcn_mfma_f32_16x16x32_f16(a, b1, acc[1][nf], 0, 0, 0);
        }
        if (ks < 7) {
            f16x8 lo, hi;
            CVT16(lo, hi);
            xs8[cur ^ 1][skh * 2 + 0][srow] = lo;
            xs8[cur ^ 1][skh * 2 + 1][srow] = hi;
            __syncthreads();
        }
    }

    const int rg = lane >> 4;
#pragma unroll
    for (int mf = 0; mf < 2; ++mf) {
        const int m = row0 + (wv << 5) + (mf << 4) + l15;
        if (m < N_NODES) {
            __half* hp = h + (size_t)m * OUT_DIM + (rg << 2);
#pragma unroll
            for (int nf = 0; nf < 8; ++nf) {
                union { ushort4 u; __half f[4]; } o;
                o.f[0] = __float2half(acc[mf][nf][0]);
                o.f[1] = __float2half(acc[mf][nf][1]);
                o.f[2] = __float2half(acc[mf][nf][2]);
                o.f[3] = __float2half(acc[mf][nf][3]);
                *(ushort4*)(hp + (nf << 4)) = o.u;
            }
        }
    }
}

// ---------------------------------------------------------------------------
// Kernel 2: per-BIN histogram (blocks 0..511) + W fp32->f16 frag transform
// (blocks 512..527, hides under the histogram; must precede gemm).
// ---------------------------------------------------------------------------
__global__ __launch_bounds__(256) void bucket_hist(const int* __restrict__ rows,
                                                   int* __restrict__ counts,
                                                   const float* __restrict__ w,
                                                   __half* __restrict__ wtl) {
    if (blockIdx.x >= HIST_BLOCKS) {
        const int e0 = ((blockIdx.x - HIST_BLOCKS) * 256 + threadIdx.x) * 8;
        const int k  = e0 >> 7;
        const int n0 = e0 & 127;
        const float4 a = *(const float4*)(w + e0);
        const float4 b = *(const float4*)(w + e0 + 4);
        __half* dst = wtl + ((size_t)((k >> 3) * 128 + n0)) * 8 + (k & 7);
        dst[0]  = __float2half(a.x);
        dst[8]  = __float2half(a.y);
        dst[16] = __float2half(a.z);
        dst[24] = __float2half(a.w);
        dst[32] = __float2half(b.x);
        dst[40] = __float2half(b.y);
        dst[48] = __float2half(b.z);
        dst[56] = __float2half(b.w);
        return;
    }

    __shared__ int lhist[NBIN];
    const int t = threadIdx.x;
    const int ebase = blockIdx.x * EPB_H;

    for (int b = t; b < NBIN; b += 256) lhist[b] = 0;
    __syncthreads();

    for (int k = 0; k < EPB_H; k += 256) {
        if (k + t < EPB_H) atomicAdd(&lhist[rows[ebase + k + t] >> BIN_SH], 1);
    }
    __syncthreads();

    for (int b = t; b < NBIN; b += 256) {
        const int c = lhist[b];
        if (c > 0) atomicAdd(&counts[b], c);
    }
}

// ---------------------------------------------------------------------------
// Kernel 3: coarse scatter into 391 bins of 128 rows (unchanged round-2;
// left the top-5). Record: { col | (row & 127) << 16 , val_bits }.
// ---------------------------------------------------------------------------
__global__ __launch_bounds__(512) void scatter_bins(const int* __restrict__ rows,
                                                    const int* __restrict__ cols,
                                                    const float* __restrict__ vals,
                                                    const int* __restrict__ counts,
                                                    int* __restrict__ cursor,
                                                    int2* __restrict__ ebuf) {
    __shared__ int sb[512];
    __shared__ int lbase[NBIN];
    const int t = threadIdx.x;
    const int ebase = blockIdx.x * EPB_S;

    sb[t] = (t < NBIN) ? counts[t] : 0;
    const int myc = sb[t];
    __syncthreads();
    for (int off = 1; off < 512; off <<= 1) {
        const int u = (t >= off) ? sb[t - off] : 0;
        __syncthreads();
        sb[t] += u;
        __syncthreads();
    }
    if (t < NBIN) lbase[t] = sb[t] - myc;
    __syncthreads();
    if (t < NBIN) sb[t] = 0;
    __syncthreads();

    int myr[SCAT_ITERS];
#pragma unroll
    for (int k = 0; k < SCAT_ITERS; ++k) {
        const int i = k * 512 + t;
        myr[k] = -1;
        if (i < EPB_S) {
            const int r = rows[ebase + i];
            myr[k] = r;
            atomicAdd(&sb[r >> BIN_SH], 1);
        }
    }
    __syncthreads();

    if (t < NBIN) {
        const int c = sb[t];
        sb[t] = (c > 0) ? (lbase[t] + atomicAdd(&cursor[t], c)) : 0;
    }
    __syncthreads();

#pragma unroll
    for (int k = 0; k < SCAT_ITERS; ++k) {
        const int i = k * 512 + t;
        if (i < EPB_S) {
            const int e = ebase + i;
            const int r = myr[k];
            const int pos = atomicAdd(&sb[r >> BIN_SH], 1);
            ebuf[pos] = make_int2(cols[e] | ((r & (BIN_ROWS - 1)) << 16), __float_as_int(vals[e]));
        }
    }
}

// ---------------------------------------------------------------------------
// Kernel 4 (FUSED sort+gather): one block per 128-row bin, 512 threads.
// Phase A: scan counts -> (base, cnt). Phase B: 2-pass counting sort of the
// bin's records from global ebuf directly into sorted LDS srec (no global
// sorted write-back, no rowoff array, no second kernel). Phase C: register
// accumulation over fp16 h (16 lanes/edge, 4 edges/wave-instr, 2 rows in
// flight), cross-group shfl reduce, fused leaky-ReLU, single out write.
// Eliminates the 25.6 MB ebuf round-trip that sort_bins+gather_rows paid.
// LDS ~40.5 KB -> 3 blocks/CU (24 waves/CU).
// ---------------------------------------------------------------------------
__global__ __launch_bounds__(512) void sort_gather(const int* __restrict__ counts,
                                                   const int2* __restrict__ ebuf,
                                                   const __half* __restrict__ h,
                                                   float* __restrict__ out) {
    __shared__ int2 srec[CAPB];            // 38 KB sorted records (aliased below)
    __shared__ int  hist[BIN_ROWS];
    __shared__ int  pfx[BIN_ROWS];
    __shared__ int  rowoff_l[BIN_ROWS + 1];
    __shared__ int  s_base, s_cnt;

    const int t   = threadIdx.x;
    const int bin = blockIdx.x;
    int* sb = (int*)srec;                  // scan scratch; dead before srec writes

    // ---- phase A: exclusive scan of bin counts -> this bin's base/cnt ----
    sb[t] = (t < NBIN) ? counts[t] : 0;
    const int myc = sb[t];
    __syncthreads();
    for (int off = 1; off < 512; off <<= 1) {
        const int u = (t >= off) ? sb[t - off] : 0;
        __syncthreads();
        sb[t] += u;
        __syncthreads();
    }
    if (t == bin) { s_base = sb[t] - myc; s_cnt = myc; }
    if (t < BIN_ROWS) hist[t] = 0;
    __syncthreads();
    const int base = s_base;
    const int cnt  = s_cnt;

    const int wv   = t >> 6;
    const int lane = t & 63;

    if (cnt <= CAPB) {
        // ---- phase B1: keys -> per-row histogram ----
        for (int i = t; i < cnt; i += 512)
            atomicAdd(&hist[(ebuf[base + i].x >> 16) & (BIN_ROWS - 1)], 1);
        __syncthreads();

        // scan 128 rows -> rowoff_l + sort cursors
        if (t < BIN_ROWS) pfx[t] = hist[t];
        __syncthreads();
        for (int off = 1; off < BIN_ROWS; off <<= 1) {
            const int u = (t >= off && t < BIN_ROWS) ? pfx[t - off] : 0;
            __syncthreads();
            if (t < BIN_ROWS) pfx[t] += u;
            __syncthreads();
        }
        if (t < BIN_ROWS) {
            const int excl = pfx[t] - hist[t];
            rowoff_l[t] = excl;
            if (t == BIN_ROWS - 1) rowoff_l[BIN_ROWS] = cnt;
            hist[t] = excl;                // sort cursor
        }
        __syncthreads();

        // ---- phase B2: sort records into LDS ----
        for (int i = t; i < cnt; i += 512) {
            const int2 r = ebuf[base + i];
            const int pos = atomicAdd(&hist[(r.x >> 16) & (BIN_ROWS - 1)], 1);
            srec[pos] = r;
        }
        __syncthreads();

        // ---- phase C: gather. 8 waves x 16 rows, pairs for MLP ----
        const int grp = lane >> 4;
        const int gl  = lane & 15;
        for (int rp = 0; rp < 8; ++rp) {
            const int lr0 = (wv << 4) + 2 * rp;
            const int lr1 = lr0 + 1;
            const int b0 = rowoff_l[lr0], e0 = rowoff_l[lr0 + 1];
            const int b1 = rowoff_l[lr1], e1 = rowoff_l[lr1 + 1];
            const int n0 = e0 - b0, n1 = e1 - b1;
            const int nmax = n0 > n1 ? n0 : n1;
            const int iters = (nmax + 3) >> 2;

            f32x8 a0 = (f32x8){0.f,0.f,0.f,0.f,0.f,0.f,0.f,0.f};
            f32x8 a1 = (f32x8){0.f,0.f,0.f,0.f,0.f,0.f,0.f,0.f};

            for (int it = 0; it < iters; ++it) {
                const int i0 = b0 + (it << 2) + grp;
                const int i1 = b1 + (it << 2) + grp;
                const bool v0i = i0 < e0;
                const bool v1i = i1 < e1;
                const int2 rA = srec[v0i ? i0 : 0];
                const int2 rB = srec[v1i ? i1 : 0];
                const float vA = v0i ? __int_as_float(rA.y) : 0.f;
                const float vB = v1i ? __int_as_float(rB.y) : 0.f;
                const f16x8 hA = *(const f16x8*)(h + (size_t)(rA.x & 0xFFFF) * OUT_DIM + (gl << 3));
                const f16x8 hB = *(const f16x8*)(h + (size_t)(rB.x & 0xFFFF) * OUT_DIM + (gl << 3));
#pragma unroll
                for (int j = 0; j < 8; ++j) {
                    a0[j] += vA * (float)hA[j];
                    a1[j] += vB * (float)hB[j];
                }
            }

#pragma unroll
            for (int j = 0; j < 8; ++j) {
                float x0 = a0[j], x1 = a1[j];
                x0 += __shfl_xor(x0, 16); x0 += __shfl_xor(x0, 32);
                x1 += __shfl_xor(x1, 16); x1 += __shfl_xor(x1, 32);
                a0[j] = x0; a1[j] = x1;
            }

            const int lrow = (grp & 2) ? lr1 : lr0;
            const int grow = (bin << BIN_SH) + lrow;
            float q[4];
#pragma unroll
            for (int k = 0; k < 4; ++k) {
                const float lo = (grp & 2) ? a1[k]     : a0[k];
                const float hi = (grp & 2) ? a1[k + 4] : a0[k + 4];
                q[k] = lrelu((grp & 1) ? hi : lo);
            }
            if (grow < N_NODES) {
                float4 o = make_float4(q[0], q[1], q[2], q[3]);
                *(float4*)(out + (size_t)grow * OUT_DIM + (gl << 3) + ((grp & 1) << 2)) = o;
            }
        }
    } else {
        // ---- overflow fallback (> +12 sigma, statistically unreachable):
        //      unsorted filter-scan straight from global ebuf ----
        for (int rr = 0; rr < 16; ++rr) {
            const int lr = (wv << 4) + rr;
            float2 acc = make_float2(0.f, 0.f);
            for (int e = 0; e < cnt; ++e) {
                const int2 rec = ebuf[base + e];
                if (((rec.x >> 16) & (BIN_ROWS - 1)) == lr) {
                    const float2 m = __half22float2(((const __half2*)(h + (size_t)(rec.x & 0xFFFF) * OUT_DIM))[lane]);
                    const float v = __int_as_float(rec.y);
                    acc.x += v * m.x; acc.y += v * m.y;
                }
            }
            const int grow = (bin << BIN_SH) + lr;
            if (grow < N_NODES) {
                acc.x = lrelu(acc.x); acc.y = lrelu(acc.y);
                ((float2*)(out + (size_t)grow * OUT_DIM))[lane] = acc;
            }
        }
    }
}

// ---------------------------------------------------------------------------
// Launch. hist(+W-convert) -> gemm -> scatter_bins -> sort_gather.
// 4 kernels + 1 memset (was 5 + memset).
// ---------------------------------------------------------------------------
extern "C" void kernel_launch(void* const* d_in, const int* in_sizes, int n_in,
                              void* d_out, int out_size, void* d_ws, size_t ws_size,
                              hipStream_t stream) {
    const float* x    = (const float*)d_in[0];
    const float* w    = (const float*)d_in[1];
    const float* vals = (const float*)d_in[2];
    const int*   rows = (const int*)d_in[3];
    const int*   cols = (const int*)d_in[4];
    float* out = (float*)d_out;

    char* ws = (char*)d_ws;
    size_t off = 0;
    auto alloc = [&](size_t bytes) {
        void* p = ws + off;
        off = (off + bytes + 255) & ~(size_t)255;
        return p;
    };
    __half* h      = (__half*)alloc((size_t)N_NODES * OUT_DIM * sizeof(__half)); // 12.8 MB
    int2*  ebuf    = (int2*) alloc((size_t)N_EDGES * sizeof(int2));              // 12.8 MB
    __half* wtl    = (__half*)alloc((size_t)IN_DIM * OUT_DIM * sizeof(__half));  // 64 KB
    int*   meta    = (int*)  alloc((size_t)(2 * NBIN) * sizeof(int));            // counts|cursor
    int*   counts  = meta;
    int*   cursor  = meta + NBIN;

    hipMemsetAsync(meta, 0, (size_t)(2 * NBIN) * sizeof(int), stream);

    bucket_hist<<<HIST_BLOCKS + CONVW_BLOCKS, 256, 0, stream>>>(rows, counts, w, wtl);
    gemm_xw_mfma<<<GEMM_BLOCKS, 256, 0, stream>>>(x, wtl, h);
    scatter_bins<<<SCAT_BLOCKS, 512, 0, stream>>>(rows, cols, vals, counts, cursor, ebuf);
    sort_gather<<<NBIN, 512, 0, stream>>>(counts, ebuf, h, out);
}

// Round 4
// 203.680 us; speedup vs baseline: 1.1716x; 1.1211x over previous
//
#include <hip/hip_runtime.h>
#include <hip/hip_fp16.h>

#define N_NODES 50000
#define N_EDGES 1600000
#define IN_DIM 256
#define OUT_DIM 128
#define NEG_SLOPE 0.01f

// ---- single-pass radix geometry: fixed-capacity strided bins ----
#define BIN_SH    5
#define BIN_ROWS  32                                    // rows per bin
#define NBIN      ((N_NODES + BIN_ROWS - 1) / BIN_ROWS) // 1563
#define CAPB      1280                                  // mean 1023, sd 32 -> +8 sigma
#define OVF_CAP   65536                                 // spill net (never used in practice)

#define SCAT_BLOCKS 256
#define CONVW_BLOCKS 8                   // extra blocks: W fp32 -> f16 frag layout
#define EPB_S (N_EDGES / SCAT_BLOCKS)    // 6250
#define SCAT_ITERS ((EPB_S + 511) / 512) // 13

typedef _Float16 f16x8 __attribute__((ext_vector_type(8)));
typedef float    f32x4 __attribute__((ext_vector_type(4)));
typedef float    f32x8 __attribute__((ext_vector_type(8)));

__device__ __forceinline__ float lrelu(float v) {
    return v >= 0.f ? v : NEG_SLOPE * v;
}

// ---------------------------------------------------------------------------
// Kernel 1: h = x @ W via v_mfma_f32_16x16x32_f16 (f16 inputs, fp32 accum).
// ~29 us, memory-bound on 51 MB x-read. Unchanged.
// ---------------------------------------------------------------------------
#define BM 128
#define GEMM_BLOCKS ((N_NODES + BM - 1) / BM)   // 391

#define CVT16(lo, hi) do { \
    lo[0]=(_Float16)xr[0].x; lo[1]=(_Float16)xr[0].y; lo[2]=(_Float16)xr[0].z; lo[3]=(_Float16)xr[0].w; \
    lo[4]=(_Float16)xr[1].x; lo[5]=(_Float16)xr[1].y; lo[6]=(_Float16)xr[1].z; lo[7]=(_Float16)xr[1].w; \
    hi[0]=(_Float16)xr[2].x; hi[1]=(_Float16)xr[2].y; hi[2]=(_Float16)xr[2].z; hi[3]=(_Float16)xr[2].w; \
    hi[4]=(_Float16)xr[3].x; hi[5]=(_Float16)xr[3].y; hi[6]=(_Float16)xr[3].z; hi[7]=(_Float16)xr[3].w; \
} while (0)

__global__ __launch_bounds__(256, 2) void gemm_xw_mfma(const float* __restrict__ x,
                                                       const __half* __restrict__ wtl,
                                                       __half* __restrict__ h) {
    __shared__ f16x8 wt8[32 * 128];   // [kgi=k/8][n] -> 8 halves k..k+7 : 64 KB
    __shared__ f16x8 xs8[2][4][BM];   // [buf][kg][m] -> 8 halves         : 16 KB

    const int t    = threadIdx.x;
    const int lane = t & 63;
    const int wv   = t >> 6;
    const int row0 = blockIdx.x * BM;

    {
        const int4* src = (const int4*)wtl;
        int4* dst = (int4*)wt8;
#pragma unroll
        for (int i = 0; i < 16; ++i) dst[i * 256 + t] = src[i * 256 + t];
    }

    const int srow = t >> 1;
    const int skh  = t & 1;
    const int grow = row0 + srow;
    const bool rv  = grow < N_NODES;
    const float* xp = x + (size_t)(rv ? grow : 0) * IN_DIM + skh * 16;

    float4 xr[4];
#pragma unroll
    for (int i = 0; i < 4; ++i)
        xr[i] = rv ? ((const float4*)xp)[i] : make_float4(0.f, 0.f, 0.f, 0.f);
    {
        f16x8 lo, hi;
        CVT16(lo, hi);
        xs8[0][skh * 2 + 0][srow] = lo;
        xs8[0][skh * 2 + 1][srow] = hi;
    }
    __syncthreads();

    f32x4 acc[2][8];
#pragma unroll
    for (int mf = 0; mf < 2; ++mf)
#pragma unroll
        for (int nf = 0; nf < 8; ++nf) acc[mf][nf] = (f32x4){0.f, 0.f, 0.f, 0.f};

    const int kg  = lane >> 4;
    const int l15 = lane & 15;
    const int mb  = (wv << 5) + l15;

#pragma unroll
    for (int ks = 0; ks < 8; ++ks) {
        const int cur = ks & 1;
        if (ks < 7) {
#pragma unroll
            for (int i = 0; i < 4; ++i)
                xr[i] = rv ? ((const float4*)(xp + (ks + 1) * 32))[i]
                           : make_float4(0.f, 0.f, 0.f, 0.f);
        }
        const f16x8 b0 = xs8[cur][kg][mb];
        const f16x8 b1 = xs8[cur][kg][mb + 16];
#pragma unroll
        for (int nf = 0; nf < 8; ++nf) {
            const f16x8 a = wt8[(((ks << 2) | kg) << 7) + (nf << 4) + l15];
            acc[0][nf] = __builtin_amdgcn_mfma_f32_16x16x32_f16(a, b0, acc[0][nf], 0, 0, 0);
            acc[1][nf] = __builtin_amdgcn_mfma_f32_16x16x32_f16(a, b1, acc[1][nf], 0, 0, 0);
        }
        if (ks < 7) {
            f16x8 lo, hi;
            CVT16(lo, hi);
            xs8[cur ^ 1][skh * 2 + 0][srow] = lo;
            xs8[cur ^ 1][skh * 2 + 1][srow] = hi;
            __syncthreads();
        }
    }

    const int rg = lane >> 4;
#pragma unroll
    for (int mf = 0; mf < 2; ++mf) {
        const int m = row0 + (wv << 5) + (mf << 4) + l15;
        if (m < N_NODES) {
            __half* hp = h + (size_t)m * OUT_DIM + (rg << 2);
#pragma unroll
            for (int nf = 0; nf < 8; ++nf) {
                union { ushort4 u; __half f[4]; } o;
                o.f[0] = __float2half(acc[mf][nf][0]);
                o.f[1] = __float2half(acc[mf][nf][1]);
                o.f[2] = __float2half(acc[mf][nf][2]);
                o.f[3] = __float2half(acc[mf][nf][3]);
                *(ushort4*)(hp + (nf << 4)) = o.u;
            }
        }
    }
}

// ---------------------------------------------------------------------------
// Kernel 2 (single-pass scatter): no histogram pre-pass, no scan. Each bin
// owns a fixed CAPB-record segment ebuf[bin*CAPB ...]; blocks reserve
// contiguous per-bin sub-ranges via one global atomic per nonempty (block,
// bin) pair. Record: { col | (row & 31) << 16 , val_bits }. Capacity spill
// (+8 sigma, ~1e-12) goes to a tagged side buffer replayed by the gather.
// Blocks >= SCAT_BLOCKS instead transform W fp32 -> f16 frag layout (wtl),
// which must precede gemm.
// ---------------------------------------------------------------------------
__global__ __launch_bounds__(512) void scatter_bins(const int* __restrict__ rows,
                                                    const int* __restrict__ cols,
                                                    const float* __restrict__ vals,
                                                    int* __restrict__ cursor,
                                                    int* __restrict__ ovfcnt,
                                                    int2* __restrict__ ebuf,
                                                    int2* __restrict__ ovfbuf,
                                                    const float* __restrict__ w,
                                                    __half* __restrict__ wtl) {
    if (blockIdx.x >= SCAT_BLOCKS) {
        // ---- W fp32 -> f16 frag-layout transform (8 blocks, 32K elems) ----
        const int e0 = ((blockIdx.x - SCAT_BLOCKS) * 512 + threadIdx.x) * 8;
        const int k  = e0 >> 7;
        const int n0 = e0 & 127;
        const float4 a = *(const float4*)(w + e0);
        const float4 b = *(const float4*)(w + e0 + 4);
        __half* dst = wtl + ((size_t)((k >> 3) * 128 + n0)) * 8 + (k & 7);
        dst[0]  = __float2half(a.x);
        dst[8]  = __float2half(a.y);
        dst[16] = __float2half(a.z);
        dst[24] = __float2half(a.w);
        dst[32] = __float2half(b.x);
        dst[40] = __float2half(b.y);
        dst[48] = __float2half(b.z);
        dst[56] = __float2half(b.w);
        return;
    }

    __shared__ int lcur[NBIN];             // 6.3 KB
    const int t = threadIdx.x;
    const int ebase = blockIdx.x * EPB_S;

    for (int b = t; b < NBIN; b += 512) lcur[b] = 0;
    __syncthreads();

    int myr[SCAT_ITERS];
#pragma unroll
    for (int k = 0; k < SCAT_ITERS; ++k) {
        const int i = k * 512 + t;
        myr[k] = -1;
        if (i < EPB_S) {
            const int r = rows[ebase + i];
            myr[k] = r;
            atomicAdd(&lcur[r >> BIN_SH], 1);
        }
    }
    __syncthreads();

    // reserve contiguous range per nonempty bin; lcur becomes running cursor
    for (int b = t; b < NBIN; b += 512) {
        const int c = lcur[b];
        lcur[b] = (c > 0) ? atomicAdd(&cursor[b], c) : 0;
    }
    __syncthreads();

#pragma unroll
    for (int k = 0; k < SCAT_ITERS; ++k) {
        const int i = k * 512 + t;
        if (i < EPB_S) {
            const int e = ebase + i;
            const int r = myr[k];
            const int bin = r >> BIN_SH;
            const int off = atomicAdd(&lcur[bin], 1);
            const int key = cols[e] | ((r & (BIN_ROWS - 1)) << 16);
            const int vb  = __float_as_int(vals[e]);
            if (off < CAPB) {
                ebuf[(size_t)bin * CAPB + off] = make_int2(key, vb);
            } else {
                const int p = atomicAdd(ovfcnt, 1);
                if (p < OVF_CAP) ovfbuf[p] = make_int2(key | (bin << 21), vb);
            }
        }
    }
}

// ---------------------------------------------------------------------------
// Kernel 3 (FUSED sort+gather), one block per 32-row bin, 512 threads.
// cnt comes straight from cursor[bin] (no scan). 2-pass counting sort from
// the bin's strided ebuf segment into ~10 KB LDS, then register-accumulation
// gather over fp16 h (16 lanes/edge, 4 edges/wave-instr, 2 rows in flight),
// cross-group shfl reduce, fused leaky-ReLU, single out write.
// 1563 blocks (6.1/CU), ~11.5 KB LDS -> wave-capped residency (4 blk/CU,
// 32 waves) vs round-3's grid-starved 27% occupancy.
// ---------------------------------------------------------------------------
__global__ __launch_bounds__(512) void sort_gather(const int* __restrict__ cursor,
                                                   const int* __restrict__ ovfcnt,
                                                   const int2* __restrict__ ebuf,
                                                   const int2* __restrict__ ovfbuf,
                                                   const __half* __restrict__ h,
                                                   float* __restrict__ out) {
    __shared__ int2 srec[CAPB];            // 10 KB sorted records
    __shared__ int  hist[BIN_ROWS];
    __shared__ int  rowoff_l[BIN_ROWS + 1];

    const int t    = threadIdx.x;
    const int bin  = blockIdx.x;
    const int wv   = t >> 6;
    const int lane = t & 63;

    const int cnt_all = cursor[bin];
    const int cnt     = cnt_all < CAPB ? cnt_all : CAPB;
    const size_t base = (size_t)bin * CAPB;

    if (t < BIN_ROWS) hist[t] = 0;
    __syncthreads();

    // ---- pass 1: keys -> per-row histogram ----
    for (int i = t; i < cnt; i += 512)
        atomicAdd(&hist[(ebuf[base + i].x >> 16) & (BIN_ROWS - 1)], 1);
    __syncthreads();

    // ---- single-wave shfl scan over 32 rows ----
    if (t < BIN_ROWS) {
        const int v = hist[t];
        int s = v;
#pragma unroll
        for (int off = 1; off < BIN_ROWS; off <<= 1) {
            const int u = __shfl_up(s, off);
            if (t >= off) s += u;
        }
        rowoff_l[t + 1] = s;
        hist[t] = s - v;                   // exclusive prefix -> sort cursor
        if (t == 0) rowoff_l[0] = 0;
    }
    __syncthreads();

    // ---- pass 2: counting sort into LDS ----
    for (int i = t; i < cnt; i += 512) {
        const int2 r = ebuf[base + i];
        const int pos = atomicAdd(&hist[(r.x >> 16) & (BIN_ROWS - 1)], 1);
        srec[pos] = r;
    }
    __syncthreads();

    // ---- gather: 8 waves x 4 rows, pairs for MLP ----
    const int grp = lane >> 4;
    const int gl  = lane & 15;
    const int novf = (cnt_all > CAPB) ? *ovfcnt : 0;   // 0 in practice

    for (int p = 0; p < 2; ++p) {
        const int lr0 = (wv << 2) + 2 * p;
        const int lr1 = lr0 + 1;
        const int b0 = rowoff_l[lr0], e0 = rowoff_l[lr0 + 1];
        const int b1 = rowoff_l[lr1], e1 = rowoff_l[lr1 + 1];
        const int n0 = e0 - b0, n1 = e1 - b1;
        const int nmax = n0 > n1 ? n0 : n1;
        const int iters = (nmax + 3) >> 2;

        f32x8 a0 = (f32x8){0.f,0.f,0.f,0.f,0.f,0.f,0.f,0.f};
        f32x8 a1 = (f32x8){0.f,0.f,0.f,0.f,0.f,0.f,0.f,0.f};

        for (int it = 0; it < iters; ++it) {
            const int i0 = b0 + (it << 2) + grp;
            const int i1 = b1 + (it << 2) + grp;
            const bool v0i = i0 < e0;
            const bool v1i = i1 < e1;
            const int2 rA = srec[v0i ? i0 : 0];
            const int2 rB = srec[v1i ? i1 : 0];
            const float vA = v0i ? __int_as_float(rA.y) : 0.f;
            const float vB = v1i ? __int_as_float(rB.y) : 0.f;
            const f16x8 hA = *(const f16x8*)(h + (size_t)(rA.x & 0xFFFF) * OUT_DIM + (gl << 3));
            const f16x8 hB = *(const f16x8*)(h + (size_t)(rB.x & 0xFFFF) * OUT_DIM + (gl << 3));
#pragma unroll
            for (int j = 0; j < 8; ++j) {
                a0[j] += vA * (float)hA[j];
                a1[j] += vB * (float)hB[j];
            }
        }

        // ---- overflow replay (novf == 0 in practice; grp 0 adds once) ----
        for (int e = 0; e < novf; ++e) {
            const int2 rec = ovfbuf[e];
            if ((rec.x >> 21) == bin && grp == 0) {
                const int lrow = (rec.x >> 16) & (BIN_ROWS - 1);
                if (lrow == lr0 || lrow == lr1) {
                    const float v = __int_as_float(rec.y);
                    const f16x8 hv = *(const f16x8*)(h + (size_t)(rec.x & 0xFFFF) * OUT_DIM + (gl << 3));
#pragma unroll
                    for (int j = 0; j < 8; ++j) {
                        if (lrow == lr0) a0[j] += v * (float)hv[j];
                        else             a1[j] += v * (float)hv[j];
                    }
                }
            }
        }

#pragma unroll
        for (int j = 0; j < 8; ++j) {
            float x0 = a0[j], x1 = a1[j];
            x0 += __shfl_xor(x0, 16); x0 += __shfl_xor(x0, 32);
            x1 += __shfl_xor(x1, 16); x1 += __shfl_xor(x1, 32);
            a0[j] = x0; a1[j] = x1;
        }

        const int lrow = (grp & 2) ? lr1 : lr0;
        const int grow = (bin << BIN_SH) + lrow;
        float q[4];
#pragma unroll
        for (int k = 0; k < 4; ++k) {
            const float lo = (grp & 2) ? a1[k]     : a0[k];
            const float hi = (grp & 2) ? a1[k + 4] : a0[k + 4];
            q[k] = lrelu((grp & 1) ? hi : lo);
        }
        if (grow < N_NODES) {
            float4 o = make_float4(q[0], q[1], q[2], q[3]);
            *(float4*)(out + (size_t)grow * OUT_DIM + (gl << 3) + ((grp & 1) << 2)) = o;
        }
    }
}

// ---------------------------------------------------------------------------
// Launch: memset -> scatter(+W-convert) -> gemm -> sort_gather.
// 4 dispatches (was 5): hist kernel and all scans eliminated.
// ---------------------------------------------------------------------------
extern "C" void kernel_launch(void* const* d_in, const int* in_sizes, int n_in,
                              void* d_out, int out_size, void* d_ws, size_t ws_size,
                              hipStream_t stream) {
    const float* x    = (const float*)d_in[0];
    const float* w    = (const float*)d_in[1];
    const float* vals = (const float*)d_in[2];
    const int*   rows = (const int*)d_in[3];
    const int*   cols = (const int*)d_in[4];
    float* out = (float*)d_out;

    char* ws = (char*)d_ws;
    size_t off = 0;
    auto alloc = [&](size_t bytes) {
        void* p = ws + off;
        off = (off + bytes + 255) & ~(size_t)255;
        return p;
    };
    __half* h      = (__half*)alloc((size_t)N_NODES * OUT_DIM * sizeof(__half));   // 12.8 MB
    int2*  ebuf    = (int2*) alloc((size_t)NBIN * CAPB * sizeof(int2));            // 16.0 MB
    int2*  ovfbuf  = (int2*) alloc((size_t)OVF_CAP * sizeof(int2));                // 0.5 MB
    __half* wtl    = (__half*)alloc((size_t)IN_DIM * OUT_DIM * sizeof(__half));    // 64 KB
    int*   meta    = (int*)  alloc((size_t)(NBIN + 1) * sizeof(int));              // cursor | ovfcnt
    int*   cursor  = meta;
    int*   ovfcnt  = meta + NBIN;

    hipMemsetAsync(meta, 0, (size_t)(NBIN + 1) * sizeof(int), stream);

    scatter_bins<<<SCAT_BLOCKS + CONVW_BLOCKS, 512, 0, stream>>>(rows, cols, vals,
                                                                 cursor, ovfcnt, ebuf, ovfbuf, w, wtl);
    gemm_xw_mfma<<<GEMM_BLOCKS, 256, 0, stream>>>(x, wtl, h);
    sort_gather<<<NBIN, 512, 0, stream>>>(cursor, ovfcnt, ebuf, ovfbuf, h, out);
}

// Round 5
// 200.584 us; speedup vs baseline: 1.1897x; 1.0154x over previous
//
#include <hip/hip_runtime.h>
#include <hip/hip_fp16.h>

#define N_NODES 50000
#define N_EDGES 1600000
#define IN_DIM 256
#define OUT_DIM 128
#define NEG_SLOPE 0.01f

// ---- two-level scatter geometry ----
#define SB_SH     10
#define SB_ROWS   1024                                  // rows per super-bin
#define NSB       ((N_NODES + SB_ROWS - 1) / SB_ROWS)   // 49
#define SB_CAP    34816                                 // mean ~32.7K, sd ~181 -> +11 sigma
#define PASSB_SPLIT 8                                   // blocks per super-bin in pass B
#define PB_ITERS  ((SB_CAP / PASSB_SPLIT + 511) / 512)  // 9

#define BIN_SH    5
#define BIN_ROWS  32                                    // rows per fine bin
#define NBIN      ((N_NODES + BIN_ROWS - 1) / BIN_ROWS) // 1563
#define NBIN_PAD  (NSB * (SB_ROWS / BIN_ROWS))          // 1568 (cursor array)
#define CAPB      1280                                  // mean 1023, sd 32 -> +8 sigma
#define OVF_CAP   65536                                 // spill net (never used in practice)

#define SCAT_BLOCKS 256
#define CONVW_BLOCKS 8                   // extra blocks: W fp32 -> f16 frag layout
#define EPB_S (N_EDGES / SCAT_BLOCKS)    // 6250
#define SCAT_ITERS ((EPB_S + 511) / 512) // 13

typedef _Float16 f16x8 __attribute__((ext_vector_type(8)));
typedef float    f32x4 __attribute__((ext_vector_type(4)));
typedef float    f32x8 __attribute__((ext_vector_type(8)));

__device__ __forceinline__ float lrelu(float v) {
    return v >= 0.f ? v : NEG_SLOPE * v;
}

// ---------------------------------------------------------------------------
// Kernel 1: h = x @ W via v_mfma_f32_16x16x32_f16 (f16 inputs, fp32 accum).
// ~29 us, memory-bound on 51 MB x-read. Unchanged.
// ---------------------------------------------------------------------------
#define BM 128
#define GEMM_BLOCKS ((N_NODES + BM - 1) / BM)   // 391

#define CVT16(lo, hi) do { \
    lo[0]=(_Float16)xr[0].x; lo[1]=(_Float16)xr[0].y; lo[2]=(_Float16)xr[0].z; lo[3]=(_Float16)xr[0].w; \
    lo[4]=(_Float16)xr[1].x; lo[5]=(_Float16)xr[1].y; lo[6]=(_Float16)xr[1].z; lo[7]=(_Float16)xr[1].w; \
    hi[0]=(_Float16)xr[2].x; hi[1]=(_Float16)xr[2].y; hi[2]=(_Float16)xr[2].z; hi[3]=(_Float16)xr[2].w; \
    hi[4]=(_Float16)xr[3].x; hi[5]=(_Float16)xr[3].y; hi[6]=(_Float16)xr[3].z; hi[7]=(_Float16)xr[3].w; \
} while (0)

__global__ __launch_bounds__(256, 2) void gemm_xw_mfma(const float* __restrict__ x,
                                                       const __half* __restrict__ wtl,
                                                       __half* __restrict__ h) {
    __shared__ f16x8 wt8[32 * 128];   // [kgi=k/8][n] -> 8 halves k..k+7 : 64 KB
    __shared__ f16x8 xs8[2][4][BM];   // [buf][kg][m] -> 8 halves         : 16 KB

    const int t    = threadIdx.x;
    const int lane = t & 63;
    const int wv   = t >> 6;
    const int row0 = blockIdx.x * BM;

    {
        const int4* src = (const int4*)wtl;
        int4* dst = (int4*)wt8;
#pragma unroll
        for (int i = 0; i < 16; ++i) dst[i * 256 + t] = src[i * 256 + t];
    }

    const int srow = t >> 1;
    const int skh  = t & 1;
    const int grow = row0 + srow;
    const bool rv  = grow < N_NODES;
    const float* xp = x + (size_t)(rv ? grow : 0) * IN_DIM + skh * 16;

    float4 xr[4];
#pragma unroll
    for (int i = 0; i < 4; ++i)
        xr[i] = rv ? ((const float4*)xp)[i] : make_float4(0.f, 0.f, 0.f, 0.f);
    {
        f16x8 lo, hi;
        CVT16(lo, hi);
        xs8[0][skh * 2 + 0][srow] = lo;
        xs8[0][skh * 2 + 1][srow] = hi;
    }
    __syncthreads();

    f32x4 acc[2][8];
#pragma unroll
    for (int mf = 0; mf < 2; ++mf)
#pragma unroll
        for (int nf = 0; nf < 8; ++nf) acc[mf][nf] = (f32x4){0.f, 0.f, 0.f, 0.f};

    const int kg  = lane >> 4;
    const int l15 = lane & 15;
    const int mb  = (wv << 5) + l15;

#pragma unroll
    for (int ks = 0; ks < 8; ++ks) {
        const int cur = ks & 1;
        if (ks < 7) {
#pragma unroll
            for (int i = 0; i < 4; ++i)
                xr[i] = rv ? ((const float4*)(xp + (ks + 1) * 32))[i]
                           : make_float4(0.f, 0.f, 0.f, 0.f);
        }
        const f16x8 b0 = xs8[cur][kg][mb];
        const f16x8 b1 = xs8[cur][kg][mb + 16];
#pragma unroll
        for (int nf = 0; nf < 8; ++nf) {
            const f16x8 a = wt8[(((ks << 2) | kg) << 7) + (nf << 4) + l15];
            acc[0][nf] = __builtin_amdgcn_mfma_f32_16x16x32_f16(a, b0, acc[0][nf], 0, 0, 0);
            acc[1][nf] = __builtin_amdgcn_mfma_f32_16x16x32_f16(a, b1, acc[1][nf], 0, 0, 0);
        }
        if (ks < 7) {
            f16x8 lo, hi;
            CVT16(lo, hi);
            xs8[cur ^ 1][skh * 2 + 0][srow] = lo;
            xs8[cur ^ 1][skh * 2 + 1][srow] = hi;
            __syncthreads();
        }
    }

    const int rg = lane >> 4;
#pragma unroll
    for (int mf = 0; mf < 2; ++mf) {
        const int m = row0 + (wv << 5) + (mf << 4) + l15;
        if (m < N_NODES) {
            __half* hp = h + (size_t)m * OUT_DIM + (rg << 2);
#pragma unroll
            for (int nf = 0; nf < 8; ++nf) {
                union { ushort4 u; __half f[4]; } o;
                o.f[0] = __float2half(acc[mf][nf][0]);
                o.f[1] = __float2half(acc[mf][nf][1]);
                o.f[2] = __float2half(acc[mf][nf][2]);
                o.f[3] = __float2half(acc[mf][nf][3]);
                *(ushort4*)(hp + (nf << 4)) = o.u;
            }
        }
    }
}

// ---------------------------------------------------------------------------
// Kernel 2 (pass A, coarse scatter): bin edges into 49 super-bins of 1024
// rows. Per (block, sbin) run ~128 records = 1 KB -> near-perfect write-line
// utilization (vs round-4's 4-record runs / 2x writeback amp). Record:
// { row<<16 | col , val_bits }. Capacity spill -> tagged side buffer.
// Blocks >= SCAT_BLOCKS transform W fp32 -> f16 frag layout (precedes gemm).
// ---------------------------------------------------------------------------
__global__ __launch_bounds__(512) void scatter_coarse(const int* __restrict__ rows,
                                                      const int* __restrict__ cols,
                                                      const float* __restrict__ vals,
                                                      int* __restrict__ sbcur,
                                                      int* __restrict__ ovfcnt,
                                                      int2* __restrict__ cbuf,
                                                      int2* __restrict__ ovfbuf,
                                                      const float* __restrict__ w,
                                                      __half* __restrict__ wtl) {
    if (blockIdx.x >= SCAT_BLOCKS) {
        // ---- W fp32 -> f16 frag-layout transform (8 blocks, 32K elems) ----
        const int e0 = ((blockIdx.x - SCAT_BLOCKS) * 512 + threadIdx.x) * 8;
        const int k  = e0 >> 7;
        const int n0 = e0 & 127;
        const float4 a = *(const float4*)(w + e0);
        const float4 b = *(const float4*)(w + e0 + 4);
        __half* dst = wtl + ((size_t)((k >> 3) * 128 + n0)) * 8 + (k & 7);
        dst[0]  = __float2half(a.x);
        dst[8]  = __float2half(a.y);
        dst[16] = __float2half(a.z);
        dst[24] = __float2half(a.w);
        dst[32] = __float2half(b.x);
        dst[40] = __float2half(b.y);
        dst[48] = __float2half(b.z);
        dst[56] = __float2half(b.w);
        return;
    }

    __shared__ int lcur[NSB];
    const int t = threadIdx.x;
    const int ebase = blockIdx.x * EPB_S;

    if (t < NSB) lcur[t] = 0;
    __syncthreads();

    int myr[SCAT_ITERS];
#pragma unroll
    for (int k = 0; k < SCAT_ITERS; ++k) {
        const int i = k * 512 + t;
        myr[k] = -1;
        if (i < EPB_S) {
            const int r = rows[ebase + i];
            myr[k] = r;
            atomicAdd(&lcur[r >> SB_SH], 1);
        }
    }
    __syncthreads();

    if (t < NSB) {
        const int c = lcur[t];
        lcur[t] = (c > 0) ? atomicAdd(&sbcur[t], c) : 0;
    }
    __syncthreads();

#pragma unroll
    for (int k = 0; k < SCAT_ITERS; ++k) {
        const int i = k * 512 + t;
        if (i < EPB_S) {
            const int e = ebase + i;
            const int r = myr[k];
            const int sb = r >> SB_SH;
            const int off = atomicAdd(&lcur[sb], 1);
            const int key = (int)(((unsigned)r << 16) | (unsigned)cols[e]);
            const int vb  = __float_as_int(vals[e]);
            if (off < SB_CAP) {
                cbuf[(size_t)sb * SB_CAP + off] = make_int2(key, vb);
            } else {
                const int p = atomicAdd(ovfcnt, 1);
                if (p < OVF_CAP) ovfbuf[p] = make_int2(key, vb);
            }
        }
    }
}

// ---------------------------------------------------------------------------
// Kernel 3 (pass B, fine scatter): 8 blocks per super-bin re-scatter its
// (L2-hot) records into the 32 fine bins it covers. Per (block, fine-bin)
// run ~136 records -> coalesced. Records register-cached (single read).
// Fine record: { col | (row & 31) << 16 , val_bits }.
// ---------------------------------------------------------------------------
__global__ __launch_bounds__(512) void scatter_fine(const int* __restrict__ sbcur,
                                                    int* __restrict__ fcur,
                                                    int* __restrict__ ovfcnt,
                                                    const int2* __restrict__ cbuf,
                                                    int2* __restrict__ ebuf,
                                                    int2* __restrict__ ovfbuf) {
    __shared__ int lcur[SB_ROWS / BIN_ROWS];   // 32
    const int t    = threadIdx.x;
    const int sb   = blockIdx.x / PASSB_SPLIT;
    const int part = blockIdx.x % PASSB_SPLIT;

    const int cnt_sb = min(sbcur[sb], SB_CAP);
    const int chunk  = (cnt_sb + PASSB_SPLIT - 1) / PASSB_SPLIT;
    const int i0 = part * chunk;
    const int i1 = min(i0 + chunk, cnt_sb);

    if (t < 32) lcur[t] = 0;
    __syncthreads();

    int2 rc[PB_ITERS];
#pragma unroll
    for (int k = 0; k < PB_ITERS; ++k) {
        const int i = i0 + k * 512 + t;
        if (i < i1) {
            rc[k] = cbuf[(size_t)sb * SB_CAP + i];
            const unsigned urow = ((unsigned)rc[k].x) >> 16;
            atomicAdd(&lcur[(urow >> BIN_SH) & 31], 1);
        }
    }
    __syncthreads();

    if (t < 32) {
        const int c = lcur[t];
        lcur[t] = (c > 0) ? atomicAdd(&fcur[(sb << 5) + t], c) : 0;
    }
    __syncthreads();

#pragma unroll
    for (int k = 0; k < PB_ITERS; ++k) {
        const int i = i0 + k * 512 + t;
        if (i < i1) {
            const unsigned urow = ((unsigned)rc[k].x) >> 16;
            const int f   = (int)(urow >> BIN_SH);
            const int off = atomicAdd(&lcur[(urow >> BIN_SH) & 31], 1);
            const int key = (rc[k].x & 0xFFFF) | (int)((urow & (BIN_ROWS - 1)) << 16);
            if (off < CAPB) {
                ebuf[(size_t)f * CAPB + off] = make_int2(key, rc[k].y);
            } else {
                const int p = atomicAdd(ovfcnt, 1);
                if (p < OVF_CAP) ovfbuf[p] = rc[k];   // full-row format
            }
        }
    }
}

// ---------------------------------------------------------------------------
// Kernel 4 (FUSED sort+gather), one block per 32-row fine bin, 512 threads.
// Counting sort by class = (row&31)*8 | col>>13: within a row, records are
// ordered by 8K-column octant (2.1 MB h slice < 4 MB L2/XCD) -> phase-local
// h access for better L2 hit on the random gather. Then register-accum
// gather (16 lanes/edge, 4 edges/wave-instr, 2 rows in flight), shfl reduce,
// fused leaky-ReLU, single out write.
// ---------------------------------------------------------------------------
#define NCLS 256

__global__ __launch_bounds__(512) void sort_gather(const int* __restrict__ fcur,
                                                   const int* __restrict__ ovfcnt,
                                                   const int2* __restrict__ ebuf,
                                                   const int2* __restrict__ ovfbuf,
                                                   const __half* __restrict__ h,
                                                   float* __restrict__ out) {
    __shared__ int2 srec[CAPB];            // 10 KB sorted records
    __shared__ int  hist[NCLS];            // class counts -> sort cursors
    __shared__ int  pfx[NCLS];
    __shared__ int  rowoff_l[BIN_ROWS + 1];

    const int t    = threadIdx.x;
    const int bin  = blockIdx.x;
    const int wv   = t >> 6;
    const int lane = t & 63;

    const int cnt_all = fcur[bin];
    const int cnt     = cnt_all < CAPB ? cnt_all : CAPB;
    const size_t base = (size_t)bin * CAPB;

    if (t < NCLS) hist[t] = 0;
    __syncthreads();

    // ---- pass 1: keys -> per-(row,octant) histogram ----
    for (int i = t; i < cnt; i += 512) {
        const int k = ebuf[base + i].x;
        atomicAdd(&hist[(((k >> 16) & 31) << 3) | ((k & 0xFFFF) >> 13)], 1);
    }
    __syncthreads();

    // ---- Hillis-Steele inclusive scan over 256 classes ----
    if (t < NCLS) pfx[t] = hist[t];
    __syncthreads();
    for (int off = 1; off < NCLS; off <<= 1) {
        const int u = (t >= off && t < NCLS) ? pfx[t - off] : 0;
        __syncthreads();
        if (t < NCLS) pfx[t] += u;
        __syncthreads();
    }
    if (t < NCLS) hist[t] = pfx[t] - hist[t];          // exclusive -> sort cursor
    if (t < BIN_ROWS) rowoff_l[t] = t ? pfx[(t << 3) - 1] : 0;
    if (t == BIN_ROWS) rowoff_l[BIN_ROWS] = cnt;
    __syncthreads();

    // ---- pass 2: counting sort into LDS ----
    for (int i = t; i < cnt; i += 512) {
        const int2 r = ebuf[base + i];
        const int cls = (((r.x >> 16) & 31) << 3) | ((r.x & 0xFFFF) >> 13);
        const int pos = atomicAdd(&hist[cls], 1);
        srec[pos] = r;
    }
    __syncthreads();

    // ---- gather: 8 waves x 4 rows, pairs for MLP ----
    const int grp = lane >> 4;
    const int gl  = lane & 15;
    int novf = *ovfcnt;                   // 0 in practice
    if (novf > OVF_CAP) novf = OVF_CAP;

    for (int p = 0; p < 2; ++p) {
        const int lr0 = (wv << 2) + 2 * p;
        const int lr1 = lr0 + 1;
        const int b0 = rowoff_l[lr0], e0 = rowoff_l[lr0 + 1];
        const int b1 = rowoff_l[lr1], e1 = rowoff_l[lr1 + 1];
        const int n0 = e0 - b0, n1 = e1 - b1;
        const int nmax = n0 > n1 ? n0 : n1;
        const int iters = (nmax + 3) >> 2;

        f32x8 a0 = (f32x8){0.f,0.f,0.f,0.f,0.f,0.f,0.f,0.f};
        f32x8 a1 = (f32x8){0.f,0.f,0.f,0.f,0.f,0.f,0.f,0.f};

        for (int it = 0; it < iters; ++it) {
            const int i0 = b0 + (it << 2) + grp;
            const int i1 = b1 + (it << 2) + grp;
            const bool v0i = i0 < e0;
            const bool v1i = i1 < e1;
            const int2 rA = srec[v0i ? i0 : 0];
            const int2 rB = srec[v1i ? i1 : 0];
            const float vA = v0i ? __int_as_float(rA.y) : 0.f;
            const float vB = v1i ? __int_as_float(rB.y) : 0.f;
            const f16x8 hA = *(const f16x8*)(h + (size_t)(rA.x & 0xFFFF) * OUT_DIM + (gl << 3));
            const f16x8 hB = *(const f16x8*)(h + (size_t)(rB.x & 0xFFFF) * OUT_DIM + (gl << 3));
#pragma unroll
            for (int j = 0; j < 8; ++j) {
                a0[j] += vA * (float)hA[j];
                a1[j] += vB * (float)hB[j];
            }
        }

        // ---- overflow replay (novf == 0 in practice; grp 0 adds once) ----
        for (int e = 0; e < novf; ++e) {
            const int2 rec = ovfbuf[e];
            const unsigned urow = ((unsigned)rec.x) >> 16;
            if ((int)(urow >> BIN_SH) == bin && grp == 0) {
                const int lrow = (int)(urow & (BIN_ROWS - 1));
                if (lrow == lr0 || lrow == lr1) {
                    const float v = __int_as_float(rec.y);
                    const f16x8 hv = *(const f16x8*)(h + (size_t)(rec.x & 0xFFFF) * OUT_DIM + (gl << 3));
#pragma unroll
                    for (int j = 0; j < 8; ++j) {
                        if (lrow == lr0) a0[j] += v * (float)hv[j];
                        else             a1[j] += v * (float)hv[j];
                    }
                }
            }
        }

#pragma unroll
        for (int j = 0; j < 8; ++j) {
            float x0 = a0[j], x1 = a1[j];
            x0 += __shfl_xor(x0, 16); x0 += __shfl_xor(x0, 32);
            x1 += __shfl_xor(x1, 16); x1 += __shfl_xor(x1, 32);
            a0[j] = x0; a1[j] = x1;
        }

        const int lrow = (grp & 2) ? lr1 : lr0;
        const int grow = (bin << BIN_SH) + lrow;
        float q[4];
#pragma unroll
        for (int k = 0; k < 4; ++k) {
            const float lo = (grp & 2) ? a1[k]     : a0[k];
            const float hi = (grp & 2) ? a1[k + 4] : a0[k + 4];
            q[k] = lrelu((grp & 1) ? hi : lo);
        }
        if (grow < N_NODES) {
            float4 o = make_float4(q[0], q[1], q[2], q[3]);
            *(float4*)(out + (size_t)grow * OUT_DIM + (gl << 3) + ((grp & 1) << 2)) = o;
        }
    }
}

// ---------------------------------------------------------------------------
// Launch: memset -> coarse scatter(+W-convert) -> fine scatter -> gemm ->
// sort_gather. cbuf (coarse records) is dead before gemm runs, so h ALIASES
// it -- workspace stays ~30 MB.
// ---------------------------------------------------------------------------
extern "C" void kernel_launch(void* const* d_in, const int* in_sizes, int n_in,
                              void* d_out, int out_size, void* d_ws, size_t ws_size,
                              hipStream_t stream) {
    const float* x    = (const float*)d_in[0];
    const float* w    = (const float*)d_in[1];
    const float* vals = (const float*)d_in[2];
    const int*   rows = (const int*)d_in[3];
    const int*   cols = (const int*)d_in[4];
    float* out = (float*)d_out;

    char* ws = (char*)d_ws;
    size_t off = 0;
    auto alloc = [&](size_t bytes) {
        void* p = ws + off;
        off = (off + bytes + 255) & ~(size_t)255;
        return p;
    };
    int2*  cbuf    = (int2*) alloc((size_t)NSB * SB_CAP * sizeof(int2));           // 13.7 MB
    __half* h      = (__half*)cbuf;   // alias: h (12.8 MB) reuses dead cbuf
    int2*  ebuf    = (int2*) alloc((size_t)NBIN * CAPB * sizeof(int2));            // 16.0 MB
    int2*  ovfbuf  = (int2*) alloc((size_t)OVF_CAP * sizeof(int2));                // 0.5 MB
    __half* wtl    = (__half*)alloc((size_t)IN_DIM * OUT_DIM * sizeof(__half));    // 64 KB
    int*   meta    = (int*)  alloc((size_t)(NSB + NBIN_PAD + 1) * sizeof(int));
    int*   sbcur   = meta;
    int*   fcur    = meta + NSB;
    int*   ovfcnt  = meta + NSB + NBIN_PAD;

    hipMemsetAsync(meta, 0, (size_t)(NSB + NBIN_PAD + 1) * sizeof(int), stream);

    scatter_coarse<<<SCAT_BLOCKS + CONVW_BLOCKS, 512, 0, stream>>>(rows, cols, vals,
                                                                   sbcur, ovfcnt, cbuf, ovfbuf, w, wtl);
    scatter_fine<<<NSB * PASSB_SPLIT, 512, 0, stream>>>(sbcur, fcur, ovfcnt, cbuf, ebuf, ovfbuf);
    gemm_xw_mfma<<<GEMM_BLOCKS, 256, 0, stream>>>(x, wtl, h);
    sort_gather<<<NBIN, 512, 0, stream>>>(fcur, ovfcnt, ebuf, ovfbuf, h, out);
}